// Round 5
// baseline (1312.776 us; speedup 1.0000x reference)
//
#include <hip/hip_runtime.h>

#define BATCH 2
#define NH    16
#define SEQ   2048
#define DH    64
#define KT    32
#define NKT   (SEQ / KT)    // 64 k-tiles

typedef __attribute__((ext_vector_type(8))) short          bf16x8;
typedef __attribute__((ext_vector_type(4))) float          f32x4;
typedef __attribute__((ext_vector_type(4))) unsigned short u16x4;
typedef __attribute__((ext_vector_type(4))) int            i32x4;

__device__ __forceinline__ unsigned short f2bf(float f) {
    union { float f; unsigned int i; } c;
    c.f = f;
    unsigned int x = c.i;
    x += 0x7fffu + ((x >> 16) & 1u);   // RNE
    return (unsigned short)(x >> 16);
}

// Raw (unconverted) K/bias/mask register tile for one 32-k block.
template<bool ISBYTE> struct RawT {
    f32x4 k[2][4];          // [mb][a0lo,a0hi,a1lo,a1hi]
    f32x4 bias[2];
    unsigned int m8[2];     // used when ISBYTE
    i32x4 mi[2];            // used when !ISBYTE
};

template<bool ISBYTE>
__global__ __launch_bounds__(128, 4)
void sdpa_mfma(const float* __restrict__ qp,
               const float* __restrict__ kp,
               const float* __restrict__ vp,
               const void*  __restrict__ mp,
               const float* __restrict__ bp,
               float* __restrict__ outp,
               float* __restrict__ attnp)
{
    // per-WAVE private LDS slices -> no __syncthreads anywhere
    __shared__ __align__(16) unsigned short VT[2][DH * 40];   // V^T tile [d][kv]
    __shared__ __align__(16) unsigned short PL[2][16 * 40];   // P tile [q][k]

    const int tid  = threadIdx.x;
    const int wid  = tid >> 6;
    const int lane = tid & 63;
    const int l15  = lane & 15;   // q-column (S^T layout: lane&15 = q, MFMA row = k)
    const int g    = lane >> 4;

    // mask layout probe (wave-uniform): packed bool bytes vs int32 0/1
    const unsigned int* mw = (const unsigned int*)mp;
    if ((__any((int)(mw[lane & 31] > 1u)) != 0) != ISBYTE) return;

    const int bid  = blockIdx.x;
    const int orig = (bid & 7) * 256 + (bid >> 3);   // bijective XCD swizzle (2048 % 8 == 0)
    const int bh   = orig >> 6;                      // 0..31 ; 4 heads per XCD -> K/V fits L2
    const int qt2  = orig & 63;
    const int b    = bh >> 4, h = bh & 15;
    const int qrow = (qt2 * 2 + wid) * 16 + l15;

    const float* kbh = kp + (size_t)bh * SEQ * DH;
    const float* vbh = vp + (size_t)bh * SEQ * DH;
    const float* biasRow = bp + ((size_t)h * SEQ + qrow) * SEQ;                  // [1,H,S,S]
    const unsigned char* maskRowB = (const unsigned char*)mp + ((size_t)b * SEQ + qrow) * SEQ;
    const int*           maskRowI = (const int*)mp + ((size_t)b * SEQ + qrow) * SEQ;
    float* attnRow = attnp + ((size_t)bh * SEQ + qrow) * SEQ;

    // Q fragments (B-operand of swapped QK^T), prescaled by 1/8 (exact in bf16)
    bf16x8 qf0, qf1;
    {
        const float* qbase = qp + ((size_t)bh * SEQ + qrow) * DH + g * 8;
        #pragma unroll
        for (int j = 0; j < 8; ++j) {
            qf0[j] = (short)f2bf(qbase[j]      * 0.125f);
            qf1[j] = (short)f2bf(qbase[32 + j] * 0.125f);
        }
    }

    auto load_raw = [&](int kb, RawT<ISBYTE>& R) {
        #pragma unroll
        for (int mb = 0; mb < 2; ++mb) {
            const float* arow = kbh + (size_t)(kb + 16 * mb + l15) * DH + g * 8;
            R.k[mb][0] = *(const f32x4*)(arow);
            R.k[mb][1] = *(const f32x4*)(arow + 4);
            R.k[mb][2] = *(const f32x4*)(arow + 32);
            R.k[mb][3] = *(const f32x4*)(arow + 36);
            const int kloc = kb + 16 * mb + 4 * g;
            R.bias[mb] = *(const f32x4*)(biasRow + kloc);
            if constexpr (ISBYTE) R.m8[mb] = *(const unsigned int*)(maskRowB + kloc);
            else                  R.mi[mb] = *(const i32x4*)(maskRowI + kloc);
        }
    };

    // S^T tile from resident regs: p[mb*4+j] = exp(score) at (k=kb+16mb+4g+j, q=qrow)
    auto compute_p = [&](const RawT<ISBYTE>& R, float p[8]) {
        #pragma unroll
        for (int mb = 0; mb < 2; ++mb) {
            bf16x8 a0, a1;
            #pragma unroll
            for (int j = 0; j < 4; ++j) {
                a0[j]     = (short)f2bf(R.k[mb][0][j]);
                a0[4 + j] = (short)f2bf(R.k[mb][1][j]);
                a1[j]     = (short)f2bf(R.k[mb][2][j]);
                a1[4 + j] = (short)f2bf(R.k[mb][3][j]);
            }
            f32x4 c = R.bias[mb];
            c = __builtin_amdgcn_mfma_f32_16x16x32_bf16(a0, qf0, c, 0, 0, 0);
            c = __builtin_amdgcn_mfma_f32_16x16x32_bf16(a1, qf1, c, 0, 0, 0);
            if constexpr (ISBYTE) {
                const unsigned int m = R.m8[mb];
                #pragma unroll
                for (int j = 0; j < 4; ++j)
                    p[mb * 4 + j] = ((m >> (8 * j)) & 0xFFu) ? 0.0f : __expf(c[j]);
            } else {
                #pragma unroll
                for (int j = 0; j < 4; ++j)
                    p[mb * 4 + j] = R.mi[mb][j] ? 0.0f : __expf(c[j]);
            }
        }
    };

    // ===== pass 1: row sums of exp(s); ping-pong double-buffered K/bias/mask =====
    float lsum = 0.0f;
    {
        RawT<ISBYTE> RA, RB;
        load_raw(0, RA);
        for (int kt = 0; kt < NKT; kt += 2) {
            float p[8];
            load_raw((kt + 1) * KT, RB);                  // issue next before consuming
            compute_p(RA, p);
            #pragma unroll
            for (int j = 0; j < 8; ++j) lsum += p[j];
            load_raw(((kt + 2) & (NKT - 1)) * KT, RA);
            compute_p(RB, p);
            #pragma unroll
            for (int j = 0; j < 8; ++j) lsum += p[j];
        }
    }
    lsum += __shfl_xor(lsum, 16, 64);   // combine the 4 lane-groups (k-ranges)
    lsum += __shfl_xor(lsum, 32, 64);
    const float rinv = 1.0f / lsum;

    // ===== pass 2: attn (f32) + O^T = V^T @ P^T; rolling K prefetch + early V issue =====
    f32x4 accO[4];
    #pragma unroll
    for (int i = 0; i < 4; ++i) accO[i] = (f32x4){0.f, 0.f, 0.f, 0.f};

    unsigned short* vtw = &VT[wid][0];
    unsigned short* pwv = &PL[wid][0];
    const int vr_ = lane & 31;          // kv row within tile
    const int vd0 = (lane >> 5) * 32;   // d range base (32 floats per lane)

    {
        RawT<ISBYTE> R;
        load_raw(0, R);
        for (int kt = 0; kt < NKT; ++kt) {
            const int kb = kt * KT;

            // issue V loads for THIS tile first (consumed after compute_p)
            f32x4 vrg[8];
            const float* vrow = vbh + (size_t)(kb + vr_) * DH + vd0;
            #pragma unroll
            for (int i = 0; i < 8; ++i) vrg[i] = *(const f32x4*)(vrow + 4 * i);

            // scores from resident K regs, then immediately re-issue K for next tile
            float p[8];
            compute_p(R, p);
            load_raw(((kt + 1) & (NKT - 1)) * KT, R);

            // stage V^T (waits on vrg; latency hidden under compute_p)
            #pragma unroll
            for (int i = 0; i < 8; ++i)
                #pragma unroll
                for (int j = 0; j < 4; ++j)
                    vtw[(vd0 + 4 * i + j) * 40 + vr_] = f2bf(vrg[i][j]);

            // normalize, write attn (f32), stash P (bf16) for PV
            #pragma unroll
            for (int mb = 0; mb < 2; ++mb) {
                f32x4 pa; u16x4 pk;
                #pragma unroll
                for (int j = 0; j < 4; ++j) {
                    const float pn = p[mb * 4 + j] * rinv;
                    pa[j] = pn;
                    pk[j] = f2bf(pn);
                }
                *(f32x4*)(attnRow + kb + 16 * mb + 4 * g) = pa;
                *(u16x4*)(pwv + l15 * 40 + 16 * mb + 4 * g) = pk;
            }

            // B-frag: P^T[kk][q]; A-frag: V^T[d][kv]
            bf16x8 pf = *(const bf16x8*)(pwv + l15 * 40 + g * 8);
            #pragma unroll
            for (int mb2 = 0; mb2 < 4; ++mb2) {
                bf16x8 vf = *(const bf16x8*)(&vtw[(16 * mb2 + l15) * 40 + g * 8]);
                accO[mb2] = __builtin_amdgcn_mfma_f32_16x16x32_bf16(vf, pf, accO[mb2], 0, 0, 0);
            }
        }
    }

    // O^T C-layout: col = q = l15, row = 4*g + reg  -> d = 16*mb2 + 4*g + j
    float* outRow = outp + ((size_t)bh * SEQ + qrow) * DH;
    #pragma unroll
    for (int mb2 = 0; mb2 < 4; ++mb2) {
        f32x4 ov;
        #pragma unroll
        for (int j = 0; j < 4; ++j) ov[j] = accO[mb2][j];
        *(f32x4*)(outRow + 16 * mb2 + 4 * g) = ov;
    }
}

extern "C" void kernel_launch(void* const* d_in, const int* in_sizes, int n_in,
                              void* d_out, int out_size, void* d_ws, size_t ws_size,
                              hipStream_t stream) {
    const float* qp = (const float*)d_in[0];
    const float* kp = (const float*)d_in[1];
    const float* vp = (const float*)d_in[2];
    const void*  mp = d_in[3];
    const float* bp = (const float*)d_in[4];

    float* outp  = (float*)d_out;
    float* attnp = outp + (size_t)BATCH * NH * SEQ * DH;   // out first, then attn (f32)

    dim3 grid(BATCH * NH * (SEQ / 32));   // 2048 blocks x 128 threads (2 waves, 16 q-rows each)
    dim3 block(128);
    // mask layout resolved on-device; mismatched instantiation exits immediately
    sdpa_mfma<true ><<<grid, block, 0, stream>>>(qp, kp, vp, mp, bp, outp, attnp);
    sdpa_mfma<false><<<grid, block, 0, stream>>>(qp, kp, vp, mp, bp, outp, attnp);
}

// Round 6
// 1028.048 us; speedup vs baseline: 1.2770x; 1.2770x over previous
//
#include <hip/hip_runtime.h>

#define BATCH 2
#define NH    16
#define SEQ   2048
#define DH    64
#define KT    32
#define NKT   (SEQ / KT)    // 64 k-tiles

typedef __attribute__((ext_vector_type(8))) short          bf16x8;
typedef __attribute__((ext_vector_type(4))) float          f32x4;
typedef __attribute__((ext_vector_type(4))) unsigned short u16x4;
typedef __attribute__((ext_vector_type(4))) int            i32x4;

__device__ __forceinline__ unsigned short f2bf(float f) {
    union { float f; unsigned int i; } c;
    c.f = f;
    unsigned int x = c.i;
    x += 0x7fffu + ((x >> 16) & 1u);   // RNE
    return (unsigned short)(x >> 16);
}

// Raw (unconverted) K/bias/mask register tile for one 32-k block.
template<bool ISBYTE> struct RawT {
    f32x4 k[2][4];          // [mb][a0lo,a0hi,a1lo,a1hi]
    f32x4 bias[2];
    unsigned int m8[2];     // used when ISBYTE
    i32x4 mi[2];            // used when !ISBYTE
};

// ============ kernel 1: single pass. attn <- UNNORMALIZED exp(s); out <- P.V/sum ============
template<bool ISBYTE>
__global__ __launch_bounds__(128)
void sdpa_pass1(const float* __restrict__ qp,
                const float* __restrict__ kp,
                const float* __restrict__ vp,
                const void*  __restrict__ mp,
                const float* __restrict__ bp,
                float* __restrict__ outp,
                float* __restrict__ attnp,
                float* __restrict__ rinvp)
{
    // per-WAVE private LDS slices -> no __syncthreads anywhere
    __shared__ __align__(16) unsigned short VT[2][DH * 40];   // V^T tile [d][kv]
    __shared__ __align__(16) unsigned short PL[2][16 * 40];   // P tile [q][k]

    const int tid  = threadIdx.x;
    const int wid  = tid >> 6;
    const int lane = tid & 63;
    const int l15  = lane & 15;   // q-column (S^T layout: lane&15 = q, MFMA row = k)
    const int g    = lane >> 4;

    // mask layout probe (wave-uniform): packed bool bytes vs int32 0/1
    const unsigned int* mw = (const unsigned int*)mp;
    if ((__any((int)(mw[lane & 31] > 1u)) != 0) != ISBYTE) return;

    const int bid  = blockIdx.x;
    const int orig = (bid & 7) * 256 + (bid >> 3);   // bijective XCD swizzle (2048 % 8 == 0)
    const int bh   = orig >> 6;                      // 4 heads per XCD -> K/V fits L2
    const int qt2  = orig & 63;
    const int b    = bh >> 4, h = bh & 15;
    const int qrow = (qt2 * 2 + wid) * 16 + l15;

    const float* kbh = kp + (size_t)bh * SEQ * DH;
    const float* vbh = vp + (size_t)bh * SEQ * DH;
    const float* biasRow = bp + ((size_t)h * SEQ + qrow) * SEQ;                  // [1,H,S,S]
    const unsigned char* maskRowB = (const unsigned char*)mp + ((size_t)b * SEQ + qrow) * SEQ;
    const int*           maskRowI = (const int*)mp + ((size_t)b * SEQ + qrow) * SEQ;
    float* attnRow = attnp + ((size_t)bh * SEQ + qrow) * SEQ;

    // Q fragments (B-operand of swapped QK^T), prescaled by 1/8 (exact in bf16)
    bf16x8 qf0, qf1;
    {
        const float* qbase = qp + ((size_t)bh * SEQ + qrow) * DH + g * 8;
        #pragma unroll
        for (int j = 0; j < 8; ++j) {
            qf0[j] = (short)f2bf(qbase[j]      * 0.125f);
            qf1[j] = (short)f2bf(qbase[32 + j] * 0.125f);
        }
    }

    auto load_raw = [&](int kb, RawT<ISBYTE>& R) {
        #pragma unroll
        for (int mb = 0; mb < 2; ++mb) {
            const float* arow = kbh + (size_t)(kb + 16 * mb + l15) * DH + g * 8;
            R.k[mb][0] = *(const f32x4*)(arow);
            R.k[mb][1] = *(const f32x4*)(arow + 4);
            R.k[mb][2] = *(const f32x4*)(arow + 32);
            R.k[mb][3] = *(const f32x4*)(arow + 36);
            const int kloc = kb + 16 * mb + 4 * g;
            R.bias[mb] = __builtin_nontemporal_load((const f32x4*)(biasRow + kloc));
            if constexpr (ISBYTE) R.m8[mb] = __builtin_nontemporal_load((const unsigned int*)(maskRowB + kloc));
            else                  R.mi[mb] = __builtin_nontemporal_load((const i32x4*)(maskRowI + kloc));
        }
    };

    // S^T tile from resident regs: p[mb*4+j] = exp(score) at (k=kb+16mb+4g+j, q=qrow)
    auto compute_p = [&](const RawT<ISBYTE>& R, float p[8]) {
        #pragma unroll
        for (int mb = 0; mb < 2; ++mb) {
            bf16x8 a0, a1;
            #pragma unroll
            for (int j = 0; j < 4; ++j) {
                a0[j]     = (short)f2bf(R.k[mb][0][j]);
                a0[4 + j] = (short)f2bf(R.k[mb][1][j]);
                a1[j]     = (short)f2bf(R.k[mb][2][j]);
                a1[4 + j] = (short)f2bf(R.k[mb][3][j]);
            }
            f32x4 c = R.bias[mb];
            c = __builtin_amdgcn_mfma_f32_16x16x32_bf16(a0, qf0, c, 0, 0, 0);
            c = __builtin_amdgcn_mfma_f32_16x16x32_bf16(a1, qf1, c, 0, 0, 0);
            if constexpr (ISBYTE) {
                const unsigned int m = R.m8[mb];
                #pragma unroll
                for (int j = 0; j < 4; ++j)
                    p[mb * 4 + j] = ((m >> (8 * j)) & 0xFFu) ? 0.0f : __expf(c[j]);
            } else {
                #pragma unroll
                for (int j = 0; j < 4; ++j)
                    p[mb * 4 + j] = R.mi[mb][j] ? 0.0f : __expf(c[j]);
            }
        }
    };

    float lsum = 0.0f;
    f32x4 accO[4];
    #pragma unroll
    for (int i = 0; i < 4; ++i) accO[i] = (f32x4){0.f, 0.f, 0.f, 0.f};

    unsigned short* vtw = &VT[wid][0];
    unsigned short* pwv = &PL[wid][0];
    const int vr_ = lane & 31;          // kv row within tile
    const int vd0 = (lane >> 5) * 32;   // d range base (32 floats per lane)

    {
        RawT<ISBYTE> R;
        load_raw(0, R);
        for (int kt = 0; kt < NKT; ++kt) {
            const int kb = kt * KT;

            // issue V loads for THIS tile first (consumed after compute_p)
            f32x4 vrg[8];
            const float* vrow = vbh + (size_t)(kb + vr_) * DH + vd0;
            #pragma unroll
            for (int i = 0; i < 8; ++i) vrg[i] = *(const f32x4*)(vrow + 4 * i);

            // scores from resident K regs, then immediately re-issue K for next tile
            float p[8];
            compute_p(R, p);
            load_raw(((kt + 1) & (NKT - 1)) * KT, R);

            // stage V^T (latency hidden under compute_p)
            #pragma unroll
            for (int i = 0; i < 8; ++i)
                #pragma unroll
                for (int j = 0; j < 4; ++j)
                    vtw[(vd0 + 4 * i + j) * 40 + vr_] = f2bf(vrg[i][j]);

            // write UNNORMALIZED attn (f32, nt), stash P (bf16) for PV, accumulate lsum
            #pragma unroll
            for (int mb = 0; mb < 2; ++mb) {
                f32x4 pa; u16x4 pk;
                #pragma unroll
                for (int j = 0; j < 4; ++j) {
                    const float pn = p[mb * 4 + j];
                    pa[j] = pn;
                    pk[j] = f2bf(pn);
                    lsum += pn;
                }
                __builtin_nontemporal_store(pa, (f32x4*)(attnRow + kb + 16 * mb + 4 * g));
                *(u16x4*)(pwv + l15 * 40 + 16 * mb + 4 * g) = pk;
            }

            // B-frag: P^T[kk][q]; A-frag: V^T[d][kv]  (unnormalized PV, f32 accum)
            bf16x8 pf = *(const bf16x8*)(pwv + l15 * 40 + g * 8);
            #pragma unroll
            for (int mb2 = 0; mb2 < 4; ++mb2) {
                bf16x8 vf = *(const bf16x8*)(&vtw[(16 * mb2 + l15) * 40 + g * 8]);
                accO[mb2] = __builtin_amdgcn_mfma_f32_16x16x32_bf16(vf, pf, accO[mb2], 0, 0, 0);
            }
        }
    }

    // full row sum: combine the 4 lane-groups (k-ranges) of this q-row
    lsum += __shfl_xor(lsum, 16, 64);
    lsum += __shfl_xor(lsum, 32, 64);
    const float rinv = 1.0f / lsum;

    if (g == 0) rinvp[(size_t)bh * SEQ + qrow] = rinv;   // for the rescale kernel

    // out = accO * rinv.  O^T C-layout: col = q = l15, row = 4*g + reg
    float* outRow = outp + ((size_t)bh * SEQ + qrow) * DH;
    #pragma unroll
    for (int mb2 = 0; mb2 < 4; ++mb2) {
        f32x4 ov;
        #pragma unroll
        for (int j = 0; j < 4; ++j) ov[j] = accO[mb2][j] * rinv;
        *(f32x4*)(outRow + 16 * mb2 + 4 * g) = ov;
    }
}

// ============ kernel 2: attn *= rinv[row] — pure streaming ============
__global__ __launch_bounds__(256)
void sdpa_rescale(float* __restrict__ attnp, const float* __restrict__ rinvp)
{
    const size_t total = (size_t)BATCH * NH * SEQ * (SEQ / 4);   // in f32x4 units
    const size_t stride = (size_t)gridDim.x * blockDim.x;
    f32x4* a4 = (f32x4*)attnp;
    for (size_t i = (size_t)blockIdx.x * blockDim.x + threadIdx.x; i < total; i += stride) {
        const float r = rinvp[i >> 9];                 // 512 f32x4 per row
        f32x4 v = __builtin_nontemporal_load(a4 + i);
        v[0] *= r; v[1] *= r; v[2] *= r; v[3] *= r;
        __builtin_nontemporal_store(v, a4 + i);
    }
}

extern "C" void kernel_launch(void* const* d_in, const int* in_sizes, int n_in,
                              void* d_out, int out_size, void* d_ws, size_t ws_size,
                              hipStream_t stream) {
    const float* qp = (const float*)d_in[0];
    const float* kp = (const float*)d_in[1];
    const float* vp = (const float*)d_in[2];
    const void*  mp = d_in[3];
    const float* bp = (const float*)d_in[4];

    float* outp  = (float*)d_out;
    float* attnp = outp + (size_t)BATCH * NH * SEQ * DH;   // out first, then attn (f32)
    float* rinvp = (float*)d_ws;                            // 2*16*2048*4 B = 256 KB scratch

    dim3 grid1(BATCH * NH * (SEQ / 32));   // 2048 blocks x 128 threads (2 waves, 16 q-rows each)
    // mask layout resolved on-device; mismatched instantiation exits immediately
    sdpa_pass1<true ><<<grid1, dim3(128), 0, stream>>>(qp, kp, vp, mp, bp, outp, attnp, rinvp);
    sdpa_pass1<false><<<grid1, dim3(128), 0, stream>>>(qp, kp, vp, mp, bp, outp, attnp, rinvp);

    sdpa_rescale<<<dim3(2048), dim3(256), 0, stream>>>(attnp, rinvp);
}

// Round 7
// 901.335 us; speedup vs baseline: 1.4565x; 1.1406x over previous
//
#include <hip/hip_runtime.h>

#define BATCH 2
#define NH    16
#define SEQ   2048
#define DH    64
#define KT    32
#define NKT   (SEQ / KT)    // 64 k-tiles

typedef __attribute__((ext_vector_type(8))) short          bf16x8;
typedef __attribute__((ext_vector_type(4))) float          f32x4;
typedef __attribute__((ext_vector_type(4))) unsigned short u16x4;
typedef __attribute__((ext_vector_type(4))) int            i32x4;

__device__ __forceinline__ unsigned short f2bf(float f) {
    union { float f; unsigned int i; } c;
    c.f = f;
    unsigned int x = c.i;
    x += 0x7fffu + ((x >> 16) & 1u);   // RNE
    return (unsigned short)(x >> 16);
}

// Raw (unconverted) K/bias/mask register tile for one 32-k block.
template<bool ISBYTE> struct RawT {
    f32x4 k[2][4];          // [mb][a0lo,a0hi,a1lo,a1hi]
    f32x4 bias[2];
    unsigned int m8[2];     // used when ISBYTE
    i32x4 mi[2];            // used when !ISBYTE
};

// ===== kernel 1: single pass. attn <- UNNORMALIZED exp(s); out <- (P.V)/lsum =====
// 1 wave per block, 16 q-rows per wave. No __syncthreads. P exchange via 1.3KB LDS;
// V consumed as B-fragments directly from global (no V LDS staging at all).
template<bool ISBYTE>
__global__ __launch_bounds__(64)
void sdpa_pass1(const float* __restrict__ qp,
                const float* __restrict__ kp,
                const float* __restrict__ vp,
                const void*  __restrict__ mp,
                const float* __restrict__ bp,
                float* __restrict__ outp,
                float* __restrict__ attnp,
                float* __restrict__ rinvp)
{
    __shared__ __align__(16) unsigned short PL[16 * 40];   // P tile [q][k], stride 40

    const int lane = threadIdx.x & 63;
    const int l15  = lane & 15;   // q-column (S^T layout of QK^T)
    const int g    = lane >> 4;

    // mask layout probe (wave-uniform): packed bool bytes vs int32 0/1
    const unsigned int* mw = (const unsigned int*)mp;
    if ((__any((int)(mw[lane & 31] > 1u)) != 0) != ISBYTE) return;

    const int bid  = blockIdx.x;
    const int orig = (bid & 7) * 512 + (bid >> 3);   // bijective XCD swizzle (4096 % 8 == 0)
    const int bh   = orig >> 7;                      // 4 heads per XCD -> K/V fits one L2
    const int qt   = orig & 127;
    const int b    = bh >> 4, h = bh & 15;
    const int qrow = qt * 16 + l15;

    const float* kbh = kp + (size_t)bh * SEQ * DH;
    const float* vbh = vp + (size_t)bh * SEQ * DH;
    const float* biasRow = bp + ((size_t)h * SEQ + qrow) * SEQ;                  // [1,H,S,S]
    const unsigned char* maskRowB = (const unsigned char*)mp + ((size_t)b * SEQ + qrow) * SEQ;
    const int*           maskRowI = (const int*)mp + ((size_t)b * SEQ + qrow) * SEQ;
    float* attnRow = attnp + ((size_t)bh * SEQ + qrow) * SEQ;

    // Q fragments (B-operand of swapped QK^T), prescaled by 1/8 (exact in bf16)
    bf16x8 qf0, qf1;
    {
        const float* qbase = qp + ((size_t)bh * SEQ + qrow) * DH + g * 8;
        #pragma unroll
        for (int j = 0; j < 8; ++j) {
            qf0[j] = (short)f2bf(qbase[j]      * 0.125f);
            qf1[j] = (short)f2bf(qbase[32 + j] * 0.125f);
        }
    }

    auto load_raw = [&](int kb, RawT<ISBYTE>& R) {
        #pragma unroll
        for (int mb = 0; mb < 2; ++mb) {
            const float* arow = kbh + (size_t)(kb + 16 * mb + l15) * DH + g * 8;
            R.k[mb][0] = *(const f32x4*)(arow);
            R.k[mb][1] = *(const f32x4*)(arow + 4);
            R.k[mb][2] = *(const f32x4*)(arow + 32);
            R.k[mb][3] = *(const f32x4*)(arow + 36);
            const int kloc = kb + 16 * mb + 4 * g;
            R.bias[mb] = __builtin_nontemporal_load((const f32x4*)(biasRow + kloc));
            if constexpr (ISBYTE) R.m8[mb] = __builtin_nontemporal_load((const unsigned int*)(maskRowB + kloc));
            else                  R.mi[mb] = __builtin_nontemporal_load((const i32x4*)(maskRowI + kloc));
        }
    };

    // S^T scores from resident regs: p[mb*4+j] = exp(s) at (k=kb+16mb+4g+j, q=qrow)
    auto compute_p = [&](const RawT<ISBYTE>& R, float p[8]) {
        #pragma unroll
        for (int mb = 0; mb < 2; ++mb) {
            bf16x8 a0, a1;
            #pragma unroll
            for (int j = 0; j < 4; ++j) {
                a0[j]     = (short)f2bf(R.k[mb][0][j]);
                a0[4 + j] = (short)f2bf(R.k[mb][1][j]);
                a1[j]     = (short)f2bf(R.k[mb][2][j]);
                a1[4 + j] = (short)f2bf(R.k[mb][3][j]);
            }
            f32x4 c = R.bias[mb];
            c = __builtin_amdgcn_mfma_f32_16x16x32_bf16(a0, qf0, c, 0, 0, 0);
            c = __builtin_amdgcn_mfma_f32_16x16x32_bf16(a1, qf1, c, 0, 0, 0);
            if constexpr (ISBYTE) {
                const unsigned int m = R.m8[mb];
                #pragma unroll
                for (int j = 0; j < 4; ++j)
                    p[mb * 4 + j] = ((m >> (8 * j)) & 0xFFu) ? 0.0f : __expf(c[j]);
            } else {
                #pragma unroll
                for (int j = 0; j < 4; ++j)
                    p[mb * 4 + j] = R.mi[mb][j] ? 0.0f : __expf(c[j]);
            }
        }
    };

    float lsum = 0.0f;
    f32x4 accO[4];   // accO[nb][r] = O[q = 16qt + 4g + r][d = 16nb + l15] (unnormalized)
    #pragma unroll
    for (int i = 0; i < 4; ++i) accO[i] = (f32x4){0.f, 0.f, 0.f, 0.f};

    {
        RawT<ISBYTE> R;
        load_raw(0, R);
        for (int kt = 0; kt < NKT; ++kt) {
            const int kb = kt * KT;

            // V B-frag loads for THIS tile, issued first (consumed after compute_p):
            // vraw[nb][j] = V[kb + 8g + j][16nb + l15]
            float vraw[4][8];
            const float* vb2 = vbh + (size_t)kb * DH + 512 * g + l15;
            #pragma unroll
            for (int nb = 0; nb < 4; ++nb)
                #pragma unroll
                for (int j = 0; j < 8; ++j)
                    vraw[nb][j] = vb2[j * 64 + 16 * nb];

            // scores from resident K regs, then immediately re-issue K for next tile
            float p[8];
            compute_p(R, p);
            load_raw(((kt + 1) & (NKT - 1)) * KT, R);

            // write UNNORMALIZED attn (f32, nt), stash P (bf16) in LDS, accumulate lsum
            #pragma unroll
            for (int mb = 0; mb < 2; ++mb) {
                f32x4 pa; u16x4 pk;
                #pragma unroll
                for (int j = 0; j < 4; ++j) {
                    const float pn = p[mb * 4 + j];
                    pa[j] = pn;
                    pk[j] = f2bf(pn);
                    lsum += pn;
                }
                __builtin_nontemporal_store(pa, (f32x4*)(attnRow + kb + 16 * mb + 4 * g));
                *(u16x4*)(PL + l15 * 40 + 16 * mb + 4 * g) = pk;   // PL[q][k]
            }

            // cvt V to bf16 B-frags (hides the PL lgkm wait)
            bf16x8 vf[4];
            #pragma unroll
            for (int nb = 0; nb < 4; ++nb)
                #pragma unroll
                for (int j = 0; j < 8; ++j)
                    vf[nb][j] = (short)f2bf(vraw[nb][j]);

            // A-frag: P[q=l15][k=8g+j] — same LDS read as before, new role
            bf16x8 pf = *(const bf16x8*)(PL + l15 * 40 + g * 8);
            #pragma unroll
            for (int nb = 0; nb < 4; ++nb)
                accO[nb] = __builtin_amdgcn_mfma_f32_16x16x32_bf16(pf, vf[nb], accO[nb], 0, 0, 0);
        }
    }

    // full row sum: combine the 4 lane-groups (k-ranges) of this q-row
    lsum += __shfl_xor(lsum, 16, 64);
    lsum += __shfl_xor(lsum, 32, 64);
    const float rinv = 1.0f / lsum;

    if (g == 0) rinvp[(size_t)bh * SEQ + qrow] = rinv;   // for the rescale kernel

    // out[q][d]: lane holds O[q=16qt+4g+r][d=16nb+l15]; rinv fetched per-row by shuffle
    float* outBase = outp + ((size_t)bh * SEQ + qt * 16) * DH;
    #pragma unroll
    for (int r = 0; r < 4; ++r) {
        const float rq = __shfl(rinv, 4 * g + r, 64);   // lane 4g+r owns q = 16qt+4g+r
        #pragma unroll
        for (int nb = 0; nb < 4; ++nb)
            outBase[(4 * g + r) * DH + 16 * nb + l15] = accO[nb][r] * rq;
    }
}

// ===== kernel 2: attn *= rinv[row] — pure streaming =====
__global__ __launch_bounds__(256)
void sdpa_rescale(float* __restrict__ attnp, const float* __restrict__ rinvp)
{
    const size_t total = (size_t)BATCH * NH * SEQ * (SEQ / 4);   // in f32x4 units
    const size_t stride = (size_t)gridDim.x * blockDim.x;
    f32x4* a4 = (f32x4*)attnp;
    for (size_t i = (size_t)blockIdx.x * blockDim.x + threadIdx.x; i < total; i += stride) {
        const float r = rinvp[i >> 9];                 // 512 f32x4 per row
        f32x4 v = __builtin_nontemporal_load(a4 + i);
        v[0] *= r; v[1] *= r; v[2] *= r; v[3] *= r;
        __builtin_nontemporal_store(v, a4 + i);
    }
}

extern "C" void kernel_launch(void* const* d_in, const int* in_sizes, int n_in,
                              void* d_out, int out_size, void* d_ws, size_t ws_size,
                              hipStream_t stream) {
    const float* qp = (const float*)d_in[0];
    const float* kp = (const float*)d_in[1];
    const float* vp = (const float*)d_in[2];
    const void*  mp = d_in[3];
    const float* bp = (const float*)d_in[4];

    float* outp  = (float*)d_out;
    float* attnp = outp + (size_t)BATCH * NH * SEQ * DH;   // out first, then attn (f32)
    float* rinvp = (float*)d_ws;                            // 256 KB scratch

    dim3 grid1(BATCH * NH * (SEQ / 16));   // 4096 blocks x 1 wave (16 q-rows each)
    // mask layout resolved on-device; mismatched instantiation exits immediately
    sdpa_pass1<true ><<<grid1, dim3(64), 0, stream>>>(qp, kp, vp, mp, bp, outp, attnp, rinvp);
    sdpa_pass1<false><<<grid1, dim3(64), 0, stream>>>(qp, kp, vp, mp, bp, outp, attnp, rinvp);

    sdpa_rescale<<<dim3(2048), dim3(256), 0, stream>>>(attnp, rinvp);
}

// Round 8
// 895.073 us; speedup vs baseline: 1.4667x; 1.0070x over previous
//
#include <hip/hip_runtime.h>

#define BATCH 2
#define NH    16
#define SEQ   2048
#define DH    64
#define KT    32
#define NKT2  32            // k-tiles per wave (K split across 2 waves)

typedef __attribute__((ext_vector_type(8))) short          bf16x8;
typedef __attribute__((ext_vector_type(4))) float          f32x4;
typedef __attribute__((ext_vector_type(4))) unsigned short u16x4;
typedef __attribute__((ext_vector_type(4))) int            i32x4;

__device__ __forceinline__ unsigned short f2bf(float f) {   // RNE (Q and P only)
    union { float f; unsigned int i; } c;
    c.f = f;
    unsigned int x = c.i;
    x += 0x7fffu + ((x >> 16) & 1u);
    return (unsigned short)(x >> 16);
}
// truncation pack: two f32 -> one u32 of 2 bf16 (round-toward-zero; 1-3 VALU)
__device__ __forceinline__ unsigned int pkt(float lo, float hi) {
    union { float f; unsigned int u; } a, b;
    a.f = lo; b.f = hi;
    return (b.u & 0xFFFF0000u) | (a.u >> 16);
}

// Raw (unconverted) K/bias/mask register tile for one 32-k block.
template<bool ISBYTE> struct RawT {
    f32x4 k[2][4];          // [mb][a0lo,a0hi,a1lo,a1hi]
    f32x4 bias[2];
    unsigned int m8[2];     // ISBYTE
    i32x4 mi[2];            // !ISBYTE
};

// ===== kernel 1: attn <- UNNORMALIZED exp(s); out <- (P.V)/lsum.  2 waves split K. =====
template<bool ISBYTE>
__global__ __launch_bounds__(128)
void sdpa_pass1(const float* __restrict__ qp,
                const float* __restrict__ kp,
                const float* __restrict__ vp,
                const void*  __restrict__ mp,
                const float* __restrict__ bp,
                float* __restrict__ outp,
                float* __restrict__ attnp,
                float* __restrict__ rinvp)
{
    __shared__ __align__(16) unsigned short PL[2][16 * 40];  // per-wave P tile [q][k]
    __shared__ float LS[2][16];                              // per-wave row sums
    __shared__ float OA[16][65];                             // accO exchange (padded)

    const int tid  = threadIdx.x;
    const int wid  = tid >> 6;          // k-half owner
    const int lane = tid & 63;
    const int l15  = lane & 15;         // q-column (S^T layout of QK^T)
    const int g    = lane >> 4;

    // mask layout probe (uniform): packed bool bytes vs int32 0/1 (exit before barriers)
    const unsigned int* mw = (const unsigned int*)mp;
    if ((__any((int)(mw[lane & 31] > 1u)) != 0) != ISBYTE) return;

    const int bid  = blockIdx.x;
    const int orig = (bid & 7) * 512 + (bid >> 3);   // bijective XCD swizzle (4096 % 8 == 0)
    const int bh   = orig >> 7;                      // 4 heads per XCD -> K/V fits one L2
    const int qt   = orig & 127;
    const int b    = bh >> 4, h = bh & 15;
    const int qrow = qt * 16 + l15;
    const int k0   = wid * (SEQ / 2);                // this wave's k-range base

    const float* kbh = kp + (size_t)bh * SEQ * DH;
    const float* vbh = vp + (size_t)bh * SEQ * DH;
    const float* biasRow = bp + ((size_t)h * SEQ + qrow) * SEQ;                  // [1,H,S,S]
    const unsigned char* maskRowB = (const unsigned char*)mp + ((size_t)b * SEQ + qrow) * SEQ;
    const int*           maskRowI = (const int*)mp + ((size_t)b * SEQ + qrow) * SEQ;
    float* attnRow = attnp + ((size_t)bh * SEQ + qrow) * SEQ;

    // Q fragments (B-operand of swapped QK^T), prescaled by 1/8 (RNE, once)
    bf16x8 qf0, qf1;
    {
        const float* qbase = qp + ((size_t)bh * SEQ + qrow) * DH + g * 8;
        #pragma unroll
        for (int j = 0; j < 8; ++j) {
            qf0[j] = (short)f2bf(qbase[j]      * 0.125f);
            qf1[j] = (short)f2bf(qbase[32 + j] * 0.125f);
        }
    }

    auto load_raw = [&](int kb, RawT<ISBYTE>& R) {
        #pragma unroll
        for (int mb = 0; mb < 2; ++mb) {
            const float* arow = kbh + (size_t)(kb + 16 * mb + l15) * DH + g * 8;
            R.k[mb][0] = *(const f32x4*)(arow);
            R.k[mb][1] = *(const f32x4*)(arow + 4);
            R.k[mb][2] = *(const f32x4*)(arow + 32);
            R.k[mb][3] = *(const f32x4*)(arow + 36);
            const int kloc = kb + 16 * mb + 4 * g;
            R.bias[mb] = __builtin_nontemporal_load((const f32x4*)(biasRow + kloc));  // stream-once
            if constexpr (ISBYTE) R.m8[mb] = *(const unsigned int*)(maskRowB + kloc); // 16x reused: cache
            else                  R.mi[mb] = *(const i32x4*)(maskRowI + kloc);
        }
    };

    // S^T scores from resident regs: p[mb*4+j] = exp(s) at (k=kb+16mb+4g+j, q=qrow)
    auto compute_p = [&](const RawT<ISBYTE>& R, float p[8]) {
        #pragma unroll
        for (int mb = 0; mb < 2; ++mb) {
            union { bf16x8 v; unsigned int u[4]; } A0, A1;
            A0.u[0] = pkt(R.k[mb][0][0], R.k[mb][0][1]);
            A0.u[1] = pkt(R.k[mb][0][2], R.k[mb][0][3]);
            A0.u[2] = pkt(R.k[mb][1][0], R.k[mb][1][1]);
            A0.u[3] = pkt(R.k[mb][1][2], R.k[mb][1][3]);
            A1.u[0] = pkt(R.k[mb][2][0], R.k[mb][2][1]);
            A1.u[1] = pkt(R.k[mb][2][2], R.k[mb][2][3]);
            A1.u[2] = pkt(R.k[mb][3][0], R.k[mb][3][1]);
            A1.u[3] = pkt(R.k[mb][3][2], R.k[mb][3][3]);
            f32x4 c = R.bias[mb];
            __builtin_amdgcn_s_setprio(1);
            c = __builtin_amdgcn_mfma_f32_16x16x32_bf16(A0.v, qf0, c, 0, 0, 0);
            c = __builtin_amdgcn_mfma_f32_16x16x32_bf16(A1.v, qf1, c, 0, 0, 0);
            __builtin_amdgcn_s_setprio(0);
            if constexpr (ISBYTE) {
                const unsigned int m = R.m8[mb];
                #pragma unroll
                for (int j = 0; j < 4; ++j)
                    p[mb * 4 + j] = ((m >> (8 * j)) & 0xFFu) ? 0.0f : __expf(c[j]);
            } else {
                #pragma unroll
                for (int j = 0; j < 4; ++j)
                    p[mb * 4 + j] = R.mi[mb][j] ? 0.0f : __expf(c[j]);
            }
        }
    };

    float lsum = 0.0f;
    f32x4 accO[4];   // accO[nb][r] = O[q = 16qt + 4g + r][d = 16nb + l15] (this k-half)
    #pragma unroll
    for (int i = 0; i < 4; ++i) accO[i] = (f32x4){0.f, 0.f, 0.f, 0.f};

    {
        RawT<ISBYTE> R;
        load_raw(k0, R);
        for (int kt = 0; kt < NKT2; ++kt) {
            const int kb = k0 + kt * KT;

            // V B-frag loads for THIS tile, issued first: vraw[nb][j] = V[kb+8g+j][16nb+l15]
            float vraw[4][8];
            const float* vb2 = vbh + (size_t)kb * DH + 512 * g + l15;
            #pragma unroll
            for (int nb = 0; nb < 4; ++nb)
                #pragma unroll
                for (int j = 0; j < 8; ++j)
                    vraw[nb][j] = vb2[j * 64 + 16 * nb];

            // scores from resident K regs, then immediately re-issue K for next tile
            float p[8];
            compute_p(R, p);
            load_raw(k0 + (((kt + 1) & (NKT2 - 1)) * KT), R);

            // write UNNORMALIZED attn (f32, nt), stash P (bf16 RNE) in LDS, accumulate lsum
            #pragma unroll
            for (int mb = 0; mb < 2; ++mb) {
                f32x4 pa; u16x4 pk;
                #pragma unroll
                for (int j = 0; j < 4; ++j) {
                    const float pn = p[mb * 4 + j];
                    pa[j] = pn;
                    pk[j] = f2bf(pn);
                    lsum += pn;
                }
                __builtin_nontemporal_store(pa, (f32x4*)(attnRow + kb + 16 * mb + 4 * g));
                *(u16x4*)(&PL[wid][0] + l15 * 40 + 16 * mb + 4 * g) = pk;
            }

            // V -> bf16 B-frags via truncation pack
            union { bf16x8 v; unsigned int u[4]; } vf[4];
            #pragma unroll
            for (int nb = 0; nb < 4; ++nb)
                #pragma unroll
                for (int i = 0; i < 4; ++i)
                    vf[nb].u[i] = pkt(vraw[nb][2 * i], vraw[nb][2 * i + 1]);

            // A-frag: P[q=l15][k=8g+j]
            bf16x8 pf = *(const bf16x8*)(&PL[wid][0] + l15 * 40 + g * 8);
            __builtin_amdgcn_s_setprio(1);
            #pragma unroll
            for (int nb = 0; nb < 4; ++nb)
                accO[nb] = __builtin_amdgcn_mfma_f32_16x16x32_bf16(pf, vf[nb].v, accO[nb], 0, 0, 0);
            __builtin_amdgcn_s_setprio(0);
        }
    }

    // intra-wave: combine the 4 lane-groups (k-subranges) of each q-row
    lsum += __shfl_xor(lsum, 16, 64);
    lsum += __shfl_xor(lsum, 32, 64);
    if (g == 0) LS[wid][l15] = lsum;

    // cross-wave accO exchange: wave1 deposits, wave0 combines + writes
    if (wid == 1) {
        #pragma unroll
        for (int nb = 0; nb < 4; ++nb)
            #pragma unroll
            for (int r = 0; r < 4; ++r)
                OA[4 * g + r][16 * nb + l15] = accO[nb][r];
    }
    __syncthreads();

    if (wid == 0) {
        const float rinv = 1.0f / (LS[0][l15] + LS[1][l15]);
        if (g == 0) rinvp[(size_t)bh * SEQ + qrow] = rinv;   // for the rescale kernel

        float* outBase = outp + ((size_t)bh * SEQ + qt * 16) * DH;
        #pragma unroll
        for (int r = 0; r < 4; ++r) {
            const float rq = __shfl(rinv, 4 * g + r, 64);    // lane 4g+r owns q-row 4g+r
            #pragma unroll
            for (int nb = 0; nb < 4; ++nb)
                outBase[(4 * g + r) * DH + 16 * nb + l15] =
                    (accO[nb][r] + OA[4 * g + r][16 * nb + l15]) * rq;
        }
    }
}

// ===== kernel 2: attn *= rinv[row] — pure streaming =====
__global__ __launch_bounds__(256)
void sdpa_rescale(float* __restrict__ attnp, const float* __restrict__ rinvp)
{
    const size_t total = (size_t)BATCH * NH * SEQ * (SEQ / 4);   // f32x4 units
    const size_t stride = (size_t)gridDim.x * blockDim.x;
    f32x4* a4 = (f32x4*)attnp;
    for (size_t i = (size_t)blockIdx.x * blockDim.x + threadIdx.x; i < total; i += stride) {
        const float r = rinvp[i >> 9];                 // 512 f32x4 per row
        f32x4 v = __builtin_nontemporal_load(a4 + i);
        v[0] *= r; v[1] *= r; v[2] *= r; v[3] *= r;
        __builtin_nontemporal_store(v, a4 + i);
    }
}

extern "C" void kernel_launch(void* const* d_in, const int* in_sizes, int n_in,
                              void* d_out, int out_size, void* d_ws, size_t ws_size,
                              hipStream_t stream) {
    const float* qp = (const float*)d_in[0];
    const float* kp = (const float*)d_in[1];
    const float* vp = (const float*)d_in[2];
    const void*  mp = d_in[3];
    const float* bp = (const float*)d_in[4];

    float* outp  = (float*)d_out;
    float* attnp = outp + (size_t)BATCH * NH * SEQ * DH;   // out first, then attn (f32)
    float* rinvp = (float*)d_ws;                            // 256 KB scratch

    dim3 grid1(BATCH * NH * (SEQ / 16));   // 4096 blocks x 2 waves (k-split)
    sdpa_pass1<true ><<<grid1, dim3(128), 0, stream>>>(qp, kp, vp, mp, bp, outp, attnp, rinvp);
    sdpa_pass1<false><<<grid1, dim3(128), 0, stream>>>(qp, kp, vp, mp, bp, outp, attnp, rinvp);

    sdpa_rescale<<<dim3(2048), dim3(256), 0, stream>>>(attnp, rinvp);
}

// Round 9
// 868.762 us; speedup vs baseline: 1.5111x; 1.0303x over previous
//
#include <hip/hip_runtime.h>

#define BATCH 2
#define NH    16
#define SEQ   2048
#define DH    64
#define KT    32
#define NKT2  32            // k-tiles per wave (K split across 2 waves)

typedef __attribute__((ext_vector_type(8))) short          bf16x8;
typedef __attribute__((ext_vector_type(4))) float          f32x4;
typedef __attribute__((ext_vector_type(4))) unsigned short u16x4;
typedef __attribute__((ext_vector_type(4))) int            i32x4;

__device__ __forceinline__ unsigned short f2bf(float f) {   // RNE (Q and P only)
    union { float f; unsigned int i; } c;
    c.f = f;
    unsigned int x = c.i;
    x += 0x7fffu + ((x >> 16) & 1u);
    return (unsigned short)(x >> 16);
}
// truncation pack: two f32 -> one u32 of 2 bf16 (round-toward-zero; 1-3 VALU)
__device__ __forceinline__ unsigned int pkt(float lo, float hi) {
    union { float f; unsigned int u; } a, b;
    a.f = lo; b.f = hi;
    return (b.u & 0xFFFF0000u) | (a.u >> 16);
}

template<bool ISBYTE> struct RawT {
    f32x4 k[2][4];          // [mb][a0lo,a0hi,a1lo,a1hi]
    f32x4 bias[2];
    unsigned int m8[2];     // ISBYTE
    i32x4 mi[2];            // !ISBYTE
};
struct VRaw { float v[4][8]; };   // vraw[nb][j] = V[kb+8g+j][16nb+l15]

// ===== kernel 1: attn <- UNNORMALIZED exp(s); out <- (P.V)/lsum.  2 waves split K. =====
template<bool ISBYTE>
__global__ __launch_bounds__(128, 2)   // min 2 waves/EU -> 256-VGPR budget, NO SPILLS
void sdpa_pass1(const float* __restrict__ qp,
                const float* __restrict__ kp,
                const float* __restrict__ vp,
                const void*  __restrict__ mp,
                const float* __restrict__ bp,
                float* __restrict__ outp,
                float* __restrict__ attnp,
                float* __restrict__ rinvp)
{
    __shared__ __align__(16) unsigned short PL[2][16 * 40];  // per-wave P tile [q][k]
    __shared__ float LS[2][16];                              // per-wave row sums
    __shared__ float OA[16][65];                             // accO exchange (padded)

    const int tid  = threadIdx.x;
    const int wid  = tid >> 6;          // k-half owner
    const int lane = tid & 63;
    const int l15  = lane & 15;         // q-column (S^T layout of QK^T)
    const int g    = lane >> 4;

    // mask layout probe (block-uniform; exit happens before any barrier)
    const unsigned int* mw = (const unsigned int*)mp;
    if ((__any((int)(mw[lane & 31] > 1u)) != 0) != ISBYTE) return;

    // swizzle: XCD x owns head-pair {2x,2x+1}, BOTH batches, b interleaved in
    // adjacent blocks so bias rows (shared by b=0/1) are L2-resident when reused.
    const int bid  = blockIdx.x;
    const int orig = (bid & 7) * 512 + (bid >> 3);   // bijective (4096 % 8 == 0)
    const int h    = orig >> 8;                      // 0..15 (2 heads per XCD)
    const int w_   = orig & 255;
    const int qt   = w_ >> 1;                        // 0..127
    const int b    = w_ & 1;
    const int bh   = b * NH + h;
    const int qrow = qt * 16 + l15;
    const int k0   = wid * (SEQ / 2);                // this wave's k-range base

    const float* kbh = kp + (size_t)bh * SEQ * DH;
    const float* vbh = vp + (size_t)bh * SEQ * DH;
    const float* biasRow = bp + ((size_t)h * SEQ + qrow) * SEQ;                  // [1,H,S,S]
    const unsigned char* maskRowB = (const unsigned char*)mp + ((size_t)b * SEQ + qrow) * SEQ;
    const int*           maskRowI = (const int*)mp + ((size_t)b * SEQ + qrow) * SEQ;
    float* attnRow = attnp + ((size_t)bh * SEQ + qrow) * SEQ;

    // Q fragments (B-operand of swapped QK^T), prescaled by 1/8 (RNE, once)
    bf16x8 qf0, qf1;
    {
        const float* qbase = qp + ((size_t)bh * SEQ + qrow) * DH + g * 8;
        #pragma unroll
        for (int j = 0; j < 8; ++j) {
            qf0[j] = (short)f2bf(qbase[j]      * 0.125f);
            qf1[j] = (short)f2bf(qbase[32 + j] * 0.125f);
        }
    }

    auto load_raw = [&](int kb, RawT<ISBYTE>& R) {
        #pragma unroll
        for (int mb = 0; mb < 2; ++mb) {
            const float* arow = kbh + (size_t)(kb + 16 * mb + l15) * DH + g * 8;
            R.k[mb][0] = *(const f32x4*)(arow);
            R.k[mb][1] = *(const f32x4*)(arow + 4);
            R.k[mb][2] = *(const f32x4*)(arow + 32);
            R.k[mb][3] = *(const f32x4*)(arow + 36);
            const int kloc = kb + 16 * mb + 4 * g;
            R.bias[mb] = __builtin_nontemporal_load((const f32x4*)(biasRow + kloc));  // stream-once
            if constexpr (ISBYTE) R.m8[mb] = *(const unsigned int*)(maskRowB + kloc);
            else                  R.mi[mb] = *(const i32x4*)(maskRowI + kloc);
        }
    };

    auto load_v = [&](int kb, VRaw& V) {
        const float* vb2 = vbh + (size_t)kb * DH + 512 * g + l15;
        #pragma unroll
        for (int nb = 0; nb < 4; ++nb)
            #pragma unroll
            for (int j = 0; j < 8; ++j)
                V.v[nb][j] = vb2[j * 64 + 16 * nb];
    };

    auto compute_p = [&](const RawT<ISBYTE>& R, float p[8]) {
        #pragma unroll
        for (int mb = 0; mb < 2; ++mb) {
            union { bf16x8 v; unsigned int u[4]; } A0, A1;
            A0.u[0] = pkt(R.k[mb][0][0], R.k[mb][0][1]);
            A0.u[1] = pkt(R.k[mb][0][2], R.k[mb][0][3]);
            A0.u[2] = pkt(R.k[mb][1][0], R.k[mb][1][1]);
            A0.u[3] = pkt(R.k[mb][1][2], R.k[mb][1][3]);
            A1.u[0] = pkt(R.k[mb][2][0], R.k[mb][2][1]);
            A1.u[1] = pkt(R.k[mb][2][2], R.k[mb][2][3]);
            A1.u[2] = pkt(R.k[mb][3][0], R.k[mb][3][1]);
            A1.u[3] = pkt(R.k[mb][3][2], R.k[mb][3][3]);
            f32x4 c = R.bias[mb];
            __builtin_amdgcn_s_setprio(1);
            c = __builtin_amdgcn_mfma_f32_16x16x32_bf16(A0.v, qf0, c, 0, 0, 0);
            c = __builtin_amdgcn_mfma_f32_16x16x32_bf16(A1.v, qf1, c, 0, 0, 0);
            __builtin_amdgcn_s_setprio(0);
            if constexpr (ISBYTE) {
                const unsigned int m = R.m8[mb];
                #pragma unroll
                for (int j = 0; j < 4; ++j)
                    p[mb * 4 + j] = ((m >> (8 * j)) & 0xFFu) ? 0.0f : __expf(c[j]);
            } else {
                #pragma unroll
                for (int j = 0; j < 4; ++j)
                    p[mb * 4 + j] = R.mi[mb][j] ? 0.0f : __expf(c[j]);
            }
        }
    };

    float lsum = 0.0f;
    f32x4 accO[4];   // accO[nb][r] = O[q=16qt+4g+r][d=16nb+l15] (this k-half)
    #pragma unroll
    for (int i = 0; i < 4; ++i) accO[i] = (f32x4){0.f, 0.f, 0.f, 0.f};

    unsigned short* plw = &PL[wid][0];

    // body for one 32-k tile: scores, attn store, P->LDS, V cvt, PV MFMA
    auto body = [&](const RawT<ISBYTE>& R, const VRaw& V, int kb) {
        float p[8];
        compute_p(R, p);
        #pragma unroll
        for (int mb = 0; mb < 2; ++mb) {
            f32x4 pa; u16x4 pk;
            #pragma unroll
            for (int j = 0; j < 4; ++j) {
                const float pn = p[mb * 4 + j];
                pa[j] = pn;
                pk[j] = f2bf(pn);
                lsum += pn;
            }
            __builtin_nontemporal_store(pa, (f32x4*)(attnRow + kb + 16 * mb + 4 * g));
            *(u16x4*)(plw + l15 * 40 + 16 * mb + 4 * g) = pk;
        }
        union { bf16x8 v; unsigned int u[4]; } vf[4];
        #pragma unroll
        for (int nb = 0; nb < 4; ++nb)
            #pragma unroll
            for (int i = 0; i < 4; ++i)
                vf[nb].u[i] = pkt(V.v[nb][2 * i], V.v[nb][2 * i + 1]);
        bf16x8 pf = *(const bf16x8*)(plw + l15 * 40 + g * 8);
        __builtin_amdgcn_s_setprio(1);
        #pragma unroll
        for (int nb = 0; nb < 4; ++nb)
            accO[nb] = __builtin_amdgcn_mfma_f32_16x16x32_bf16(pf, vf[nb].v, accO[nb], 0, 0, 0);
        __builtin_amdgcn_s_setprio(0);
    };

    {
        RawT<ISBYTE> RA, RB;
        VRaw VA, VB;
        load_raw(k0, RA);
        load_v(k0, VA);
        for (int kt = 0; kt < NKT2; kt += 2) {
            const int kb0 = k0 + kt * KT;
            const int kb1 = k0 + (kt + 1) * KT;
            const int kb2 = k0 + (((kt + 2) & (NKT2 - 1)) * KT);
            load_raw(kb1, RB);  load_v(kb1, VB);   // full-tile-ahead prefetch
            body(RA, VA, kb0);
            load_raw(kb2, RA);  load_v(kb2, RA.k[0][0][0] == 0.f && false ? VA : VA);  // placeholder no-op guard
            load_v(kb2, VA);
            body(RB, VB, kb1);
        }
    }

    // intra-wave: combine the 4 lane-groups (k-subranges) of each q-row
    lsum += __shfl_xor(lsum, 16, 64);
    lsum += __shfl_xor(lsum, 32, 64);
    if (g == 0) LS[wid][l15] = lsum;

    // cross-wave accO exchange: wave1 deposits, wave0 combines + writes
    if (wid == 1) {
        #pragma unroll
        for (int nb = 0; nb < 4; ++nb)
            #pragma unroll
            for (int r = 0; r < 4; ++r)
                OA[4 * g + r][16 * nb + l15] = accO[nb][r];
    }
    __syncthreads();

    if (wid == 0) {
        const float rinv = 1.0f / (LS[0][l15] + LS[1][l15]);
        if (g == 0) rinvp[(size_t)bh * SEQ + qrow] = rinv;

        float* outBase = outp + ((size_t)bh * SEQ + qt * 16) * DH;
        #pragma unroll
        for (int r = 0; r < 4; ++r) {
            const float rq = __shfl(rinv, 4 * g + r, 64);
            #pragma unroll
            for (int nb = 0; nb < 4; ++nb)
                outBase[(4 * g + r) * DH + 16 * nb + l15] =
                    (accO[nb][r] + OA[4 * g + r][16 * nb + l15]) * rq;
        }
    }
}

// ===== kernel 2: attn *= rinv[row] — pure streaming =====
__global__ __launch_bounds__(256)
void sdpa_rescale(float* __restrict__ attnp, const float* __restrict__ rinvp)
{
    const size_t total = (size_t)BATCH * NH * SEQ * (SEQ / 4);   // f32x4 units
    const size_t stride = (size_t)gridDim.x * blockDim.x;
    f32x4* a4 = (f32x4*)attnp;
    for (size_t i = (size_t)blockIdx.x * blockDim.x + threadIdx.x; i < total; i += stride) {
        const float r = rinvp[i >> 9];                 // 512 f32x4 per row
        f32x4 v = __builtin_nontemporal_load(a4 + i);
        v[0] *= r; v[1] *= r; v[2] *= r; v[3] *= r;
        __builtin_nontemporal_store(v, a4 + i);
    }
}

extern "C" void kernel_launch(void* const* d_in, const int* in_sizes, int n_in,
                              void* d_out, int out_size, void* d_ws, size_t ws_size,
                              hipStream_t stream) {
    const float* qp = (const float*)d_in[0];
    const float* kp = (const float*)d_in[1];
    const float* vp = (const float*)d_in[2];
    const void*  mp = d_in[3];
    const float* bp = (const float*)d_in[4];

    float* outp  = (float*)d_out;
    float* attnp = outp + (size_t)BATCH * NH * SEQ * DH;   // out first, then attn (f32)
    float* rinvp = (float*)d_ws;                            // 256 KB scratch

    dim3 grid1(BATCH * NH * (SEQ / 16));   // 4096 blocks x 2 waves (k-split)
    sdpa_pass1<true ><<<grid1, dim3(128), 0, stream>>>(qp, kp, vp, mp, bp, outp, attnp, rinvp);
    sdpa_pass1<false><<<grid1, dim3(128), 0, stream>>>(qp, kp, vp, mp, bp, outp, attnp, rinvp);

    sdpa_rescale<<<dim3(2048), dim3(256), 0, stream>>>(attnp, rinvp);
}

// Round 10
// 813.998 us; speedup vs baseline: 1.6128x; 1.0673x over previous
//
#include <hip/hip_runtime.h>

#define BATCH 2
#define NH    16
#define SEQ   2048
#define DH    64
#define KT    32
#define NKT2  32            // k-tiles per wave (K split across 2 waves)

typedef __attribute__((ext_vector_type(8))) short          bf16x8;
typedef __attribute__((ext_vector_type(4))) float          f32x4;
typedef __attribute__((ext_vector_type(4))) unsigned short u16x4;
typedef __attribute__((ext_vector_type(4))) int            i32x4;

__device__ __forceinline__ unsigned short f2bf(float f) {   // RNE (Q and P only)
    union { float f; unsigned int i; } c;
    c.f = f;
    unsigned int x = c.i;
    x += 0x7fffu + ((x >> 16) & 1u);
    return (unsigned short)(x >> 16);
}
// truncation pack: two f32 -> one u32 of 2 bf16 (round-toward-zero; 1-3 VALU)
__device__ __forceinline__ unsigned int pkt(float lo, float hi) {
    union { float f; unsigned int u; } a, b;
    a.f = lo; b.f = hi;
    return (b.u & 0xFFFF0000u) | (a.u >> 16);
}

template<bool ISBYTE> struct RawT {
    f32x4 k[2][4];          // [mb][a0lo,a0hi,a1lo,a1hi]
    f32x4 bias[2];
    unsigned int m8[2];     // ISBYTE
    i32x4 mi[2];            // !ISBYTE
};
struct VRaw { float v[4][8]; };   // v[nb][j] = V[kb+8g+j][16nb+l15]

// ===== kernel 1: attn <- UNNORMALIZED exp(s); out <- (P.V)/lsum.  2 waves split K. =====
template<bool ISBYTE>
__global__ __launch_bounds__(128, 2)
void sdpa_pass1(const float* __restrict__ qp,
                const float* __restrict__ kp,
                const float* __restrict__ vp,
                const void*  __restrict__ mp,
                const float* __restrict__ bp,
                float* __restrict__ outp,
                float* __restrict__ attnp,
                float* __restrict__ rinvp)
{
    __shared__ __align__(16) unsigned short PL[2][16 * 40];  // per-wave P tile [q][k]
    __shared__ float LS[2][16];                              // per-wave row sums
    __shared__ float OA[16][65];                             // accO exchange (padded)

    const int tid  = threadIdx.x;
    const int wid  = tid >> 6;          // k-half owner
    const int lane = tid & 63;
    const int l15  = lane & 15;         // q-column (S^T layout of QK^T)
    const int g    = lane >> 4;

    // mask layout probe (block-uniform; exit happens before any barrier)
    const unsigned int* mw = (const unsigned int*)mp;
    if ((__any((int)(mw[lane & 31] > 1u)) != 0) != ISBYTE) return;

    // swizzle: XCD x owns head-pair {2x,2x+1}, both batches; b in adjacent blocks
    // so bias rows (shared by b=0/1) are L2-resident when reused (CACHED loads!).
    const int bid  = blockIdx.x;
    const int orig = (bid & 7) * 512 + (bid >> 3);   // bijective (4096 % 8 == 0)
    const int h    = orig >> 8;
    const int w_   = orig & 255;
    const int qt   = w_ >> 1;
    const int b    = w_ & 1;
    const int bh   = b * NH + h;
    const int qrow = qt * 16 + l15;
    const int k0   = wid * (SEQ / 2);

    const float* kbh = kp + (size_t)bh * SEQ * DH;
    const float* vbh = vp + (size_t)bh * SEQ * DH;
    const float* biasRow = bp + ((size_t)h * SEQ + qrow) * SEQ;                  // [1,H,S,S]
    const unsigned char* maskRowB = (const unsigned char*)mp + ((size_t)b * SEQ + qrow) * SEQ;
    const int*           maskRowI = (const int*)mp + ((size_t)b * SEQ + qrow) * SEQ;
    float* attnRow = attnp + ((size_t)bh * SEQ + qrow) * SEQ;

    // Q fragments (B-operand of swapped QK^T), prescaled by 1/8 (RNE, once)
    bf16x8 qf0, qf1;
    {
        const float* qbase = qp + ((size_t)bh * SEQ + qrow) * DH + g * 8;
        #pragma unroll
        for (int j = 0; j < 8; ++j) {
            qf0[j] = (short)f2bf(qbase[j]      * 0.125f);
            qf1[j] = (short)f2bf(qbase[32 + j] * 0.125f);
        }
    }

    auto load_raw = [&](int kb, RawT<ISBYTE>& R) {
        #pragma unroll
        for (int mb = 0; mb < 2; ++mb) {
            const float* arow = kbh + (size_t)(kb + 16 * mb + l15) * DH + g * 8;
            R.k[mb][0] = *(const f32x4*)(arow);
            R.k[mb][1] = *(const f32x4*)(arow + 4);
            R.k[mb][2] = *(const f32x4*)(arow + 32);
            R.k[mb][3] = *(const f32x4*)(arow + 36);
            const int kloc = kb + 16 * mb + 4 * g;
            R.bias[mb] = *(const f32x4*)(biasRow + kloc);     // CACHED: b-pair shares in L2
            if constexpr (ISBYTE) R.m8[mb] = *(const unsigned int*)(maskRowB + kloc);
            else                  R.mi[mb] = *(const i32x4*)(maskRowI + kloc);
        }
    };

    auto load_v = [&](int kb, VRaw& V) {
        const float* vb2 = vbh + (size_t)kb * DH + 512 * g + l15;
        #pragma unroll
        for (int nb = 0; nb < 4; ++nb)
            #pragma unroll
            for (int j = 0; j < 8; ++j)
                V.v[nb][j] = vb2[j * 64 + 16 * nb];
    };

    auto compute_p = [&](const RawT<ISBYTE>& R, float p[8]) {
        #pragma unroll
        for (int mb = 0; mb < 2; ++mb) {
            union { bf16x8 v; unsigned int u[4]; } A0, A1;
            A0.u[0] = pkt(R.k[mb][0][0], R.k[mb][0][1]);
            A0.u[1] = pkt(R.k[mb][0][2], R.k[mb][0][3]);
            A0.u[2] = pkt(R.k[mb][1][0], R.k[mb][1][1]);
            A0.u[3] = pkt(R.k[mb][1][2], R.k[mb][1][3]);
            A1.u[0] = pkt(R.k[mb][2][0], R.k[mb][2][1]);
            A1.u[1] = pkt(R.k[mb][2][2], R.k[mb][2][3]);
            A1.u[2] = pkt(R.k[mb][3][0], R.k[mb][3][1]);
            A1.u[3] = pkt(R.k[mb][3][2], R.k[mb][3][3]);
            f32x4 c = R.bias[mb];
            __builtin_amdgcn_s_setprio(1);
            c = __builtin_amdgcn_mfma_f32_16x16x32_bf16(A0.v, qf0, c, 0, 0, 0);
            c = __builtin_amdgcn_mfma_f32_16x16x32_bf16(A1.v, qf1, c, 0, 0, 0);
            __builtin_amdgcn_s_setprio(0);
            if constexpr (ISBYTE) {
                const unsigned int m = R.m8[mb];
                #pragma unroll
                for (int j = 0; j < 4; ++j)
                    p[mb * 4 + j] = ((m >> (8 * j)) & 0xFFu) ? 0.0f : __expf(c[j]);
            } else {
                #pragma unroll
                for (int j = 0; j < 4; ++j)
                    p[mb * 4 + j] = R.mi[mb][j] ? 0.0f : __expf(c[j]);
            }
        }
    };

    float lsum = 0.0f;
    f32x4 accO[4];   // accO[nb][r] = O[q=16qt+4g+r][d=16nb+l15] (this k-half)
    #pragma unroll
    for (int i = 0; i < 4; ++i) accO[i] = (f32x4){0.f, 0.f, 0.f, 0.f};

    unsigned short* plw = &PL[wid][0];

    auto body = [&](const RawT<ISBYTE>& R, const VRaw& V, int kb) {
        float p[8];
        compute_p(R, p);
        #pragma unroll
        for (int mb = 0; mb < 2; ++mb) {
            f32x4 pa; u16x4 pk;
            #pragma unroll
            for (int j = 0; j < 4; ++j) {
                const float pn = p[mb * 4 + j];
                pa[j] = pn;
                pk[j] = f2bf(pn);
                lsum += pn;
            }
            *(f32x4*)(attnRow + kb + 16 * mb + 4 * g) = pa;      // CACHED store (no nt amp)
            *(u16x4*)(plw + l15 * 40 + 16 * mb + 4 * g) = pk;
        }
        union { bf16x8 v; unsigned int u[4]; } vf[4];
        #pragma unroll
        for (int nb = 0; nb < 4; ++nb)
            #pragma unroll
            for (int i = 0; i < 4; ++i)
                vf[nb].u[i] = pkt(V.v[nb][2 * i], V.v[nb][2 * i + 1]);
        bf16x8 pf = *(const bf16x8*)(plw + l15 * 40 + g * 8);
        __builtin_amdgcn_s_setprio(1);
        #pragma unroll
        for (int nb = 0; nb < 4; ++nb)
            accO[nb] = __builtin_amdgcn_mfma_f32_16x16x32_bf16(pf, vf[nb].v, accO[nb], 0, 0, 0);
        __builtin_amdgcn_s_setprio(0);
    };

    {
        RawT<ISBYTE> RA, RB;
        VRaw VA, VB;
        load_raw(k0, RA);           load_v(k0, VA);          // prologue: tiles 0,1
        load_raw(k0 + KT, RB);      load_v(k0 + KT, VB);
        for (int kt = 0; kt < NKT2; kt += 2) {
            const int kb0 = k0 + kt * KT;
            const int kb2 = k0 + (((kt + 2) & (NKT2 - 1)) * KT);
            const int kb3 = k0 + (((kt + 3) & (NKT2 - 1)) * KT);
            body(RA, VA, kb0);                       // consume slot A (tile t)
            load_raw(kb2, RA);  load_v(kb2, VA);     // reissue A for t+2 -> ~2 bodies in flight
            body(RB, VB, kb0 + KT);                  // consume slot B (tile t+1)
            load_raw(kb3, RB);  load_v(kb3, VB);     // reissue B for t+3
        }
    }

    // intra-wave: combine the 4 lane-groups (k-subranges) of each q-row
    lsum += __shfl_xor(lsum, 16, 64);
    lsum += __shfl_xor(lsum, 32, 64);
    if (g == 0) LS[wid][l15] = lsum;

    // cross-wave accO exchange: wave1 deposits, wave0 combines + writes
    if (wid == 1) {
        #pragma unroll
        for (int nb = 0; nb < 4; ++nb)
            #pragma unroll
            for (int r = 0; r < 4; ++r)
                OA[4 * g + r][16 * nb + l15] = accO[nb][r];
    }
    __syncthreads();

    if (wid == 0) {
        const float rinv = 1.0f / (LS[0][l15] + LS[1][l15]);
        if (g == 0) rinvp[(size_t)bh * SEQ + qrow] = rinv;

        float* outBase = outp + ((size_t)bh * SEQ + qt * 16) * DH;
        #pragma unroll
        for (int r = 0; r < 4; ++r) {
            const float rq = __shfl(rinv, 4 * g + r, 64);
            #pragma unroll
            for (int nb = 0; nb < 4; ++nb)
                outBase[(4 * g + r) * DH + 16 * nb + l15] =
                    (accO[nb][r] + OA[4 * g + r][16 * nb + l15]) * rq;
        }
    }
}

// ===== kernel 2: attn *= rinv[row] — pure streaming (cached; nt caused write amp) =====
__global__ __launch_bounds__(256)
void sdpa_rescale(float* __restrict__ attnp, const float* __restrict__ rinvp)
{
    const size_t total = (size_t)BATCH * NH * SEQ * (SEQ / 4);   // f32x4 units
    const size_t stride = (size_t)gridDim.x * blockDim.x;
    f32x4* a4 = (f32x4*)attnp;
    for (size_t i = (size_t)blockIdx.x * blockDim.x + threadIdx.x; i < total; i += stride) {
        const float r = rinvp[i >> 9];                 // 512 f32x4 per row
        f32x4 v = a4[i];
        v[0] *= r; v[1] *= r; v[2] *= r; v[3] *= r;
        a4[i] = v;
    }
}

extern "C" void kernel_launch(void* const* d_in, const int* in_sizes, int n_in,
                              void* d_out, int out_size, void* d_ws, size_t ws_size,
                              hipStream_t stream) {
    const float* qp = (const float*)d_in[0];
    const float* kp = (const float*)d_in[1];
    const float* vp = (const float*)d_in[2];
    const void*  mp = d_in[3];
    const float* bp = (const float*)d_in[4];

    float* outp  = (float*)d_out;
    float* attnp = outp + (size_t)BATCH * NH * SEQ * DH;   // out first, then attn (f32)
    float* rinvp = (float*)d_ws;                            // 256 KB scratch

    dim3 grid1(BATCH * NH * (SEQ / 16));   // 4096 blocks x 2 waves (k-split)
    sdpa_pass1<true ><<<grid1, dim3(128), 0, stream>>>(qp, kp, vp, mp, bp, outp, attnp, rinvp);
    sdpa_pass1<false><<<grid1, dim3(128), 0, stream>>>(qp, kp, vp, mp, bp, outp, attnp, rinvp);

    sdpa_rescale<<<dim3(2048), dim3(256), 0, stream>>>(attnp, rinvp);
}